// Round 4
// baseline (109.396 us; speedup 1.0000x reference)
//
#include <hip/hip_runtime.h>
#include <math.h>

#define IMG   512
#define NIMG  24
#define XST   104    // X stride (halfs), rows 16B-aligned
#define TST   104    // T' stride (row length 96)
#define RST   88     // R stride (row length 80)
#define UST   88     // U' stride (row length 80)

// ---- LDS pool layout (units: halfs), 64x64 output tile ----
// A: reads X [16896,26880), writes sTL/sTH [0,16640)
// B: reads sT,              writes R0..R2 [16896,38016)  (over dead X)
// C: reads R,               writes U0..U2 [0,16896)      (over dead sT)
// D: reads U.   ftab [38016,39328) written once pre-barrier, read into regs.
#define SA_TL  0        // 80*104 = 8320
#define SA_TH  8320     // -> 16640
#define SA_X   16896    // 96*104 = 9984 -> 26880 (dead after A)
#define SA_R   16896    // 3 x 80*88 = 21120 -> 38016
#define RSZ    7040
#define SA_U   0        // 3 x 64*88 = 16896 -> 16896
#define USZ    5632
#define SA_FT  38016    // 4 modes x 41 starts x 8 = 1312 -> 39328
#define POOLSZ 39328    // 78656 B -> 2 blocks/CU

typedef _Float16 v8h __attribute__((ext_vector_type(8)));
typedef float    v4f __attribute__((ext_vector_type(4)));

__device__ __forceinline__ v8h load8(const _Float16* p) {
    union { uint4 u; v8h h; } c;
    c.u = *(const uint4*)p;
    return c.h;
}

__device__ __forceinline__ unsigned pkrtz(float a, float b) {
    union { __fp16 __attribute__((ext_vector_type(2))) v; unsigned u; } c;
    c.v = __builtin_amdgcn_cvt_pkrtz(a, b);
    return c.u;
}

__device__ __forceinline__ void store4(_Float16* p, v4f a) {
    union { _Float16 h[4]; uint2 u; } c;
    c.h[0] = (_Float16)a[0]; c.h[1] = (_Float16)a[1];
    c.h[2] = (_Float16)a[2]; c.h[3] = (_Float16)a[3];
    *(uint2*)p = c.u;
}

__device__ __forceinline__ void store4abs(_Float16* p, v4f a) {
    union { _Float16 h[4]; uint2 u; } c;
    c.h[0] = (_Float16)fabsf(a[0]); c.h[1] = (_Float16)fabsf(a[1]);
    c.h[2] = (_Float16)fabsf(a[2]); c.h[3] = (_Float16)fabsf(a[3]);
    *(uint2*)p = c.u;
}

// float -> bf16 bits, round-to-nearest-even (input non-NaN)
__device__ __forceinline__ unsigned short f2bf(float f) {
    unsigned b = __float_as_uint(f);
    b = (b + 0x7fffu + ((b >> 16) & 1u)) >> 16;
    return (unsigned short)b;
}

__device__ __forceinline__ int refl(int g) {
    return g < 0 ? -g : (g >= IMG ? 2 * IMG - 2 - g : g);
}

// ---------------- stage 1: MFMA banded-conv pipeline, 64x64 tile ----------------
// modes: 0: h[v]  1: lpdf[v]=(-1)^v h[15-v]  2: |h[v]|  3: |h[15-v]|
__global__ __launch_bounds__(512, 4) void stego_stage1(
    const float* __restrict__ x, const float* __restrict__ hpdf,
    unsigned short* __restrict__ rho_out, float2* __restrict__ bmm)
{
    __shared__ __align__(16) _Float16 pool[POOLSZ];
    __shared__ float red[16];

    const int tid = threadIdx.x;
    const int lane = tid & 63;
    const int wid = __builtin_amdgcn_readfirstlane(tid >> 6);   // wave-uniform -> SALU
    const int n16 = lane & 15, quad = lane >> 4;

    // XCD-swizzled block decode: all 64 tiles of an image land on one XCD's L2
    const int blk = blockIdx.x;
    const int xcd = blk & 7;
    const int grp = blk >> 3;                 // 0..191
    const int img = xcd + ((grp >> 6) << 3);  // XCD c serves images {c, c+8, c+16}
    const int tl  = grp & 63;
    const int Oi = (tl >> 3) << 6;
    const int Oj = (tl & 7) << 6;
    const float* ximg = x + (size_t)img * (IMG * IMG);

    // ---- fragment-window table: ftab[(mode*41 + s)*8 + j] = c_mode[s + j - 16] ----
    for (int e = tid; e < 1312; e += 512) {
        const int mode = e / 328;
        const int rem  = e - mode * 328;
        const int tap  = (rem >> 3) + (rem & 7) - 16;      // s + j - 16
        float v = 0.f;
        if (tap >= 0 && tap <= 15) {
            int idx = (mode == 0 || mode == 2) ? tap : 15 - tap;
            float c = hpdf[idx];
            if (mode == 1 && (tap & 1)) c = -c;
            if (mode >= 2) c = fabsf(c);
            v = c;
        }
        pool[SA_FT + e] = (_Float16)v;
    }

    // ---- load X as fp16: rows Oi-15..Oi+78 (94 rows), cols Oj-16..Oj+79 (96 cols),
    //      rows 94..95 zeroed. 2304 float4-tasks over 512 threads. ----
    if (Oi >= 15 && Oi <= 433 && Oj >= 16 && Oj <= 432) {
        const float* src = ximg + (size_t)(Oi - 15) * IMG + (Oj - 16);
        for (int p = tid; p < 2304; p += 512) {
            const int row = p / 24, cg = p - row * 24;
            uint2 pv = make_uint2(0u, 0u);
            if (row < 94) {
                float4 xv = *(const float4*)(src + (size_t)row * IMG + 4 * cg);
                pv.x = pkrtz(xv.x, xv.y);
                pv.y = pkrtz(xv.z, xv.w);
            }
            *(uint2*)(pool + SA_X + row * XST + 4 * cg) = pv;
        }
    } else {
        for (int p = tid; p < 2304; p += 512) {
            const int row = p / 24, cg = p - row * 24;
            uint2 pv = make_uint2(0u, 0u);
            if (row < 94) {
                const float* rsrc = ximg + (size_t)refl(Oi - 15 + row) * IMG;
                const int c0 = Oj - 16 + 4 * cg;
                pv.x = pkrtz(rsrc[refl(c0)],     rsrc[refl(c0 + 1)]);
                pv.y = pkrtz(rsrc[refl(c0 + 2)], rsrc[refl(c0 + 3)]);
            }
            *(uint2*)(pool + SA_X + row * XST + 4 * cg) = pv;
        }
    }
    __syncthreads();

    // ---- band fragments: one aligned ds_read_b128 per fragment.
    // band[4]: UNSHIFTED  B[k][n] = c[k-n]    (phases B, C, D)
    // bandA[2]: SHIFTED   B[k][n] = c[k-n-1]  (phase A only; X starts at Oj-16)
    v8h band[4], bandA[2];
    {
        const int sA = 16 + quad * 8 - n16;   // in [1,40]
        #pragma unroll
        for (int m = 0; m < 4; ++m)
            band[m] = load8(pool + SA_FT + (m * 41 + sA) * 8);
        #pragma unroll
        for (int m = 0; m < 2; ++m)
            bandA[m] = load8(pool + SA_FT + (m * 41 + sA - 1) * 8);
    }

    // ---- phase A: hconv X -> T_L', T_H' (30 tiles, shared A-frag, 2 MFMA each) ----
    for (int u = wid; u < 30; u += 8) {
        int mt = u % 6, nt = u / 6;
        int m0 = mt * 16, n0 = nt * 16;
        v8h a = load8(pool + SA_X + (m0 + n16) * XST + n0 + quad * 8);
        v4f z = {0.f, 0.f, 0.f, 0.f};
        v4f cL = __builtin_amdgcn_mfma_f32_16x16x32_f16(a, bandA[1], z, 0, 0, 0);
        v4f cH = __builtin_amdgcn_mfma_f32_16x16x32_f16(a, bandA[0], z, 0, 0, 0);
        int off = (n0 + n16) * TST + m0 + quad * 4;   // T'[col][row..row+3]
        store4(pool + SA_TL + off, cL);
        store4(pool + SA_TH + off, cH);
    }
    __syncthreads();

    float rho[2][4] = {{0.f, 0.f, 0.f, 0.f}, {0.f, 0.f, 0.f, 0.f}};
    const int fB[3] = {0, 1, 0};   // HL: a=H, LH: a=L, HH: a=H
    const int fC[3] = {2, 3, 3};   // b2 mode
    const int fD[3] = {3, 2, 3};   // a2 mode
    const int rotB[3] = {0, 3, 6}; // per-filter start rotation: balance 10/9 tiles/wave
    const int rotC[3] = {0, 4, 2}; // balance 8/7 tiles/wave

    // ---- phase B (fused over filters): vconv T -> R_f = |.| (75 tiles) ----
    #pragma unroll
    for (int f = 0; f < 3; ++f) {
        const _Float16* Tsrc = pool + (f == 0 ? SA_TL : SA_TH);
        _Float16* Rf = pool + SA_R + f * RSZ;
        for (int u = (wid + rotB[f]) & 7; u < 25; u += 8) {
            int nt = u % 5, mt = u / 5;
            int i0 = nt * 16, c0 = mt * 16;
            v8h a = load8(Tsrc + (c0 + n16) * TST + i0 + quad * 8);
            v4f z = {0.f, 0.f, 0.f, 0.f};
            v4f acc = __builtin_amdgcn_mfma_f32_16x16x32_f16(a, band[fB[f]], z, 0, 0, 0);
            store4abs(Rf + (i0 + n16) * RST + c0 + quad * 4, acc);
        }
    }
    __syncthreads();

    // ---- phase C (fused): hconv R_f -> U'_f (60 tiles) ----
    #pragma unroll
    for (int f = 0; f < 3; ++f) {
        const _Float16* Rf = pool + SA_R + f * RSZ;
        _Float16* Uf = pool + SA_U + f * USZ;
        for (int u = (wid + rotC[f]) & 7; u < 20; u += 8) {
            int mt = u % 5, nt = u / 5;
            int i0 = mt * 16, j0 = nt * 16;
            v8h a = load8(Rf + (i0 + n16) * RST + j0 + quad * 8);
            v4f z = {0.f, 0.f, 0.f, 0.f};
            v4f acc = __builtin_amdgcn_mfma_f32_16x16x32_f16(a, band[fC[f]], z, 0, 0, 0);
            store4(Uf + (j0 + n16) * UST + i0 + quad * 4, acc);
        }
    }
    __syncthreads();

    // ---- phase D (fused): vconv U_f -> xi; rho += 1/xi (48 tiles, 2 tiles/wave) ----
    #pragma unroll
    for (int s = 0; s < 2; ++s) {
        const int v = 2 * wid + s;
        const int i0 = (v & 3) << 4, c0 = (v >> 2) << 4;
        #pragma unroll
        for (int f = 0; f < 3; ++f) {
            const _Float16* Uf = pool + SA_U + f * USZ;
            v8h a = load8(Uf + (c0 + n16) * UST + i0 + quad * 8);
            v4f z = {0.f, 0.f, 0.f, 0.f};
            v4f acc = __builtin_amdgcn_mfma_f32_16x16x32_f16(a, band[fD[f]], z, 0, 0, 0);
            #pragma unroll
            for (int r = 0; r < 4; ++r) rho[s][r] += __builtin_amdgcn_rcpf(acc[r]);
        }
    }

    // ---- finalize: clamp/NaN, bf16 round, NATURAL-layout aligned uint2 stores;
    //      roll applied at stage2 read. Per-block min/max over 8 values. ----
    const size_t rbase = (size_t)img * (IMG * IMG);
    float lmin = 1e38f, lmax = 0.f;
    #pragma unroll
    for (int s = 0; s < 2; ++s) {
        const int v = 2 * wid + s;
        const int i_nat = Oi + ((v & 3) << 4) + n16;
        const int jb = Oj + ((v >> 2) << 4) + quad * 4;
        unsigned short b[4];
        #pragma unroll
        for (int r = 0; r < 4; ++r) {
            float w = rho[s][r];
            w = isnan(w) ? 1e10f : fminf(w, 1e10f);
            b[r] = f2bf(w);
            float rq = __uint_as_float((unsigned)b[r] << 16);
            lmin = fminf(lmin, rq);
            lmax = fmaxf(lmax, rq);
        }
        unsigned pk0 = (unsigned)b[0] | ((unsigned)b[1] << 16);
        unsigned pk1 = (unsigned)b[2] | ((unsigned)b[3] << 16);
        *(uint2*)(rho_out + rbase + ((size_t)i_nat << 9) + jb) = make_uint2(pk0, pk1);
    }

    #pragma unroll
    for (int off = 32; off >= 1; off >>= 1) {
        lmin = fminf(lmin, __shfl_xor(lmin, off));
        lmax = fmaxf(lmax, __shfl_xor(lmax, off));
    }
    if ((tid & 63) == 0) { red[wid] = lmin; red[8 + wid] = lmax; }
    __syncthreads();
    if (tid == 0) {
        float m0 = red[0], m1 = red[8];
        #pragma unroll
        for (int k = 1; k < 8; ++k) { m0 = fminf(m0, red[k]); m1 = fmaxf(m1, red[8 + k]); }
        bmm[(img << 6) + tl] = make_float2(m0, m1);
    }
}

// ---------------- stage 2: reduce minmax + rolled read + normalize + sigmoid + multiply ----------------
__global__ __launch_bounds__(256) void stego_stage2(
    const float* __restrict__ x, const unsigned short* __restrict__ rho,
    const float2* __restrict__ bmm, float* __restrict__ out)
{
    __shared__ float sred[2];
    const int tid = threadIdx.x;
    const int lane = tid & 63;

    // same XCD swizzle as stage1: read rho/x from the L2 that produced them
    const int blk = blockIdx.x;
    const int xcd = blk & 7, grp = blk >> 3;
    const int img = xcd + ((grp >> 7) << 3);
    const int chunk = grp & 127;                 // 128 blocks per image, 4 rows each
    const int t = (img << 15) + (chunk << 8) + tid;

    if (tid < 64) {
        float2 p = bmm[(img << 6) + tid];
        float lmn = p.x, lmx = p.y;
        #pragma unroll
        for (int off = 32; off >= 1; off >>= 1) {
            lmn = fminf(lmn, __shfl_xor(lmn, off));
            lmx = fmaxf(lmx, __shfl_xor(lmx, off));
        }
        if (tid == 0) { sred[0] = lmn; sred[1] = lmx; }
    }
    __syncthreads();
    const float mn = sred[0];
    const float mx = sred[1];
    const float inv = __builtin_amdgcn_rcpf(mx - mn + 1e-8f);

    // rolled rho: rho_rolled[i][j] = rho_nat[(i-1)&511][(j-1)&511].
    // One wave == one 512-px row, so the j-1 shift is a single intra-wave shfl.
    const int i = (t >> 6) & 511;
    const int rrow = (i - 1) & 511;
    const size_t rb_off = ((size_t)img << 18) + ((size_t)rrow << 9) + ((size_t)lane << 3);
    uint4 rb = *(const uint4*)(rho + rb_off);
    unsigned ru[4] = {rb.x, rb.y, rb.z, rb.w};
    float f7 = __uint_as_float(ru[3] & 0xffff0000u);   // nat col 8*lane+7
    float r[8];
    r[0] = __shfl(f7, (lane + 63) & 63);               // prev lane's col 7 (wraps to col 511)
    r[1] = __uint_as_float(ru[0] << 16);
    r[2] = __uint_as_float(ru[0] & 0xffff0000u);
    r[3] = __uint_as_float(ru[1] << 16);
    r[4] = __uint_as_float(ru[1] & 0xffff0000u);
    r[5] = __uint_as_float(ru[2] << 16);
    r[6] = __uint_as_float(ru[2] & 0xffff0000u);
    r[7] = __uint_as_float(ru[3] << 16);

    const size_t base = (size_t)t << 3;
    const float* xrow = x + base;
    float4 xa = *(const float4*)xrow;
    float4 xb = *(const float4*)(xrow + 4);
    float xs[8] = {xa.x, xa.y, xa.z, xa.w, xb.x, xb.y, xb.z, xb.w};
    float os[8];
    #pragma unroll
    for (int k = 0; k < 8; ++k) {
        float rn = (r[k] - mn) * inv;
        os[k] = xs[k] * __builtin_amdgcn_rcpf(1.f + __expf(rn - 1.f));  // x * sigmoid(1-rn)
    }
    float* orow = out + base;
    *(float4*)orow       = make_float4(os[0], os[1], os[2], os[3]);
    *(float4*)(orow + 4) = make_float4(os[4], os[5], os[6], os[7]);
}

extern "C" void kernel_launch(void* const* d_in, const int* in_sizes, int n_in,
                              void* d_out, int out_size, void* d_ws, size_t ws_size,
                              hipStream_t stream) {
    const float* x    = (const float*)d_in[0];
    const float* hpdf = (const float*)d_in[1];
    float* out = (float*)d_out;

    unsigned short* rho = (unsigned short*)d_ws;                         // 24*512*512 bf16
    float2* bmm = (float2*)((char*)d_ws + (size_t)NIMG * IMG * IMG * 2); // 24*64 float2

    hipLaunchKernelGGL(stego_stage1, dim3(NIMG * 64), dim3(512), 0, stream,
                       x, hpdf, rho, bmm);
    hipLaunchKernelGGL(stego_stage2, dim3(NIMG * 128), dim3(256), 0, stream,
                       x, rho, bmm, out);
}